// Round 1
// baseline (354.722 us; speedup 1.0000x reference)
//
#include <hip/hip_runtime.h>
#include <float.h>

// Problem constants
#define B_    16
#define NODE_ 32
#define DEG_  64
#define KNN_  8
#define INF_  128
#define ROWS_ 2048      // NODE*DEG
#define JDIM_ 8192      // DEG*INF

// ws layout (float offsets)
#define OFF_X     0                    // [16][2048] float4 (x0,x1,x2,xx)  = 131072 floats
#define OFF_Y     131072               // [16][32][8192]                    = 4194304 floats
#define OFF_ROOT  (OFF_Y + 4194304)    // [16][32][4]                       = 2048
#define OFF_WL12  (OFF_ROOT + 2048)    // [128][4]                          = 512
#define OFF_EFF   (OFF_WL12 + 512)     // [0..17]=Weff[3][6], [24..26]=beff = 32

__device__ __forceinline__ float med3f(float a, float b, float c) {
    return __builtin_amdgcn_fmed3f(a, b, c);
}
__device__ __forceinline__ float leaky(float v) { return v >= 0.f ? v : 0.2f * v; }

// ---------------- Kernel A: tiny precomputes ----------------
__global__ __launch_bounds__(128) void kA(
    const float* __restrict__ t0, const float* __restrict__ t1, const float* __restrict__ t2,
    const float* __restrict__ t3, const float* __restrict__ t4, const float* __restrict__ t5,
    const float* __restrict__ Wr0, const float* __restrict__ Wr1, const float* __restrict__ Wr2,
    const float* __restrict__ Wr3, const float* __restrict__ Wr4, const float* __restrict__ Wr5,
    const float* __restrict__ Wl1, const float* __restrict__ Wl2,
    const float* __restrict__ c1w, const float* __restrict__ c1b,
    const float* __restrict__ c2w, const float* __restrict__ c2b,
    float* __restrict__ ws)
{
    const int blk = blockIdx.x, tid = threadIdx.x;
    if (blk == 0) {
        // Wl12[i][c] = sum_s Wl1[i,s]*Wl2[s,c]   (i=tid<128)
        const float* wp = Wl1 + tid * 1280;
        float a0 = 0.f, a1 = 0.f, a2 = 0.f;
        for (int s = 0; s < 1280; ++s) {
            float w = wp[s];
            a0 = fmaf(w, Wl2[s * 3 + 0], a0);
            a1 = fmaf(w, Wl2[s * 3 + 1], a1);
            a2 = fmaf(w, Wl2[s * 3 + 2], a2);
        }
        float* o = ws + OFF_WL12 + tid * 4;
        o[0] = a0; o[1] = a1; o[2] = a2; o[3] = 0.f;
    } else if (blk <= 12) {
        // root: 1536 outputs over blocks 1..12
        int idx = (blk - 1) * 128 + tid;           // 0..1535
        int c = idx % 3, n = (idx / 3) & 31, b = idx / 96;
        float acc = 0.f;
#define TREE(T, W, RN, F) { \
        const float* tp = T + (b * RN + ((n * RN) >> 5)) * F; \
        for (int k = 0; k < F; ++k) acc = fmaf(tp[k], W[k * 3 + c], acc); }
        TREE(t0, Wr0, 1, 96)
        TREE(t1, Wr1, 2, 256)
        TREE(t2, Wr2, 4, 256)
        TREE(t3, Wr3, 8, 256)
        TREE(t4, Wr4, 16, 128)
        TREE(t5, Wr5, 32, 128)
#undef TREE
        ws[OFF_ROOT + (b * 32 + n) * 4 + c] = acc;
    } else {
        // Weff[p][c] = sum_o c2w[p,o]*c1w[o,c];  beff[p] = sum_o c2w[p,o]*c1b[o] + c2b[p]
        if (tid < 18) {
            int p = tid / 6, c = tid % 6;
            float a = 0.f;
            for (int o = 0; o < 64; ++o) a = fmaf(c2w[p * 64 + o], c1w[o * 6 + c], a);
            ws[OFF_EFF + tid] = a;
        } else if (tid < 21) {
            int p = tid - 18;
            float a = c2b[p];
            for (int o = 0; o < 64; ++o) a = fmaf(c2w[p * 64 + o], c1b[o], a);
            ws[OFF_EFF + 24 + p] = a;
        }
    }
}

// ---------------- Kernel B1: Y = leaky(t5 @ W_branch) ----------------
// grid 1024 = 32 n * 32 jtiles, block 256: thread -> one j column, all 16 b
__global__ __launch_bounds__(256) void kB1(const float* __restrict__ t5,
                                           const float* __restrict__ Wb,
                                           float* __restrict__ ws)
{
    const int n = blockIdx.x >> 5, jt = blockIdx.x & 31, tid = threadIdx.x;
    __shared__ float ts[128 * 16];                 // [k][b]
    for (int q = tid; q < 2048; q += 256) {
        int b = q >> 7, k = q & 127;
        ts[k * 16 + b] = t5[b * 4096 + n * 128 + k];
    }
    __syncthreads();
    const int j = jt * 256 + tid;
    const float* wp = Wb + n * 1048576 + j;
    float acc[16];
#pragma unroll
    for (int b = 0; b < 16; ++b) acc[b] = 0.f;
#pragma unroll 4
    for (int k = 0; k < 128; ++k) {
        float w = wp[k * 8192];
        const float4* tk = (const float4*)(ts + (k << 4));
        float4 a0 = tk[0], a1 = tk[1], a2 = tk[2], a3 = tk[3];
        acc[0]  = fmaf(a0.x, w, acc[0]);  acc[1]  = fmaf(a0.y, w, acc[1]);
        acc[2]  = fmaf(a0.z, w, acc[2]);  acc[3]  = fmaf(a0.w, w, acc[3]);
        acc[4]  = fmaf(a1.x, w, acc[4]);  acc[5]  = fmaf(a1.y, w, acc[5]);
        acc[6]  = fmaf(a1.z, w, acc[6]);  acc[7]  = fmaf(a1.w, w, acc[7]);
        acc[8]  = fmaf(a2.x, w, acc[8]);  acc[9]  = fmaf(a2.y, w, acc[9]);
        acc[10] = fmaf(a2.z, w, acc[10]); acc[11] = fmaf(a2.w, w, acc[11]);
        acc[12] = fmaf(a3.x, w, acc[12]); acc[13] = fmaf(a3.y, w, acc[13]);
        acc[14] = fmaf(a3.z, w, acc[14]); acc[15] = fmaf(a3.w, w, acc[15]);
    }
    float* yp = ws + OFF_Y + n * 8192 + j;
#pragma unroll
    for (int b = 0; b < 16; ++b) yp[b * 262144] = leaky(acc[b]);
}

// ---------------- Kernel B2: x = root + Y @ Wl12, pack (x0,x1,x2,xx) ----------------
__global__ __launch_bounds__(256) void kB2(float* __restrict__ ws)
{
    __shared__ float wl[512];
    const int tid = threadIdx.x;
    for (int q = tid; q < 512; q += 256) wl[q] = ws[OFF_WL12 + q];
    __syncthreads();
    const int gid = blockIdx.x * 256 + tid;
    const int b = gid >> 11, r = gid & 2047, n = r >> 6;
    const float* rt = ws + OFF_ROOT + ((b * 32 + n) << 2);
    float x0 = rt[0], x1 = rt[1], x2 = rt[2];
    const float4* yp = (const float4*)(ws + OFF_Y + (size_t)(b * 32 + n) * 8192 + ((r & 63) << 7));
#pragma unroll 8
    for (int i4 = 0; i4 < 32; ++i4) {
        float4 y = yp[i4];
        const float4* wr = ((const float4*)wl) + (i4 << 2);
        float4 w0 = wr[0], w1 = wr[1], w2 = wr[2], w3 = wr[3];
        x0 = fmaf(y.x, w0.x, x0); x0 = fmaf(y.y, w1.x, x0); x0 = fmaf(y.z, w2.x, x0); x0 = fmaf(y.w, w3.x, x0);
        x1 = fmaf(y.x, w0.y, x1); x1 = fmaf(y.y, w1.y, x1); x1 = fmaf(y.z, w2.y, x1); x1 = fmaf(y.w, w3.y, x1);
        x2 = fmaf(y.x, w0.z, x2); x2 = fmaf(y.y, w1.z, x2); x2 = fmaf(y.z, w2.z, x2); x2 = fmaf(y.w, w3.z, x2);
    }
    float xx = fmaf(x0, x0, fmaf(x1, x1, x2 * x2));
    ((float4*)(ws + OFF_X))[gid] = make_float4(x0, x1, x2, xx);
}

// ---------------- Kernel C: exact knn top-8 + fused edge-conv output ----------------
// grid 1024 = 16 b * 64 rowtiles(32 rows), block 256: 8 lanes (parts) per row
#define CAP_ 16
#define CSWAPD(a, b) { float _hi = fmaxf(a, b), _lo = fminf(a, b); a = _hi; b = _lo; }
__global__ __launch_bounds__(256) void kC(const float* __restrict__ ws,
                                          const float* __restrict__ bias,
                                          float* __restrict__ out)
{
    const int bb = blockIdx.x >> 6, rtile = blockIdx.x & 63, tid = threadIdx.x;
    __shared__ float4 xs[2048];
    __shared__ float eff[32];
    __shared__ int cnt[32];
    __shared__ int lists[32][CAP_];
    __shared__ int sel[32][KNN_];

    const float4* xg = (const float4*)(ws + OFF_X) + bb * 2048;
    for (int q = tid; q < 2048; q += 256) xs[q] = xg[q];
    if (tid < 32) { eff[tid] = ws[OFF_EFF + tid]; cnt[tid] = 0; }
    __syncthreads();

    const int lr = tid >> 3;          // local row 0..31
    const int part = tid & 7;
    const int r = rtile * 32 + lr;
    const float4 xr = xs[r];

    // pass 1: branchless exact top-8 VALUES (per part over m = mm*8+part)
    float s0 = -FLT_MAX, s1 = -FLT_MAX, s2 = -FLT_MAX, s3 = -FLT_MAX;
    float s4 = -FLT_MAX, s5 = -FLT_MAX, s6 = -FLT_MAX, s7 = -FLT_MAX;
#pragma unroll 4
    for (int mm = 0; mm < 256; ++mm) {
        float4 xm = xs[(mm << 3) | part];
        float dot = fmaf(xr.x, xm.x, fmaf(xr.y, xm.y, xr.z * xm.z));
        float pd = fmaf(2.f, dot, -(xr.w + xm.w));
        s7 = med3f(pd, s7, s6); s6 = med3f(pd, s6, s5);
        s5 = med3f(pd, s5, s4); s4 = med3f(pd, s4, s3);
        s3 = med3f(pd, s3, s2); s2 = med3f(pd, s2, s1);
        s1 = med3f(pd, s1, s0); s0 = fmaxf(s0, pd);
    }
    // merge across the 8 parts (same 8-lane group): bitonic half-clean + re-sort
#pragma unroll
    for (int w = 1; w < 8; w <<= 1) {
        float o0 = __shfl_xor(s0, w), o1 = __shfl_xor(s1, w), o2 = __shfl_xor(s2, w), o3 = __shfl_xor(s3, w);
        float o4 = __shfl_xor(s4, w), o5 = __shfl_xor(s5, w), o6 = __shfl_xor(s6, w), o7 = __shfl_xor(s7, w);
        float n0 = fmaxf(s0, o7), n1 = fmaxf(s1, o6), n2 = fmaxf(s2, o5), n3 = fmaxf(s3, o4);
        float n4 = fmaxf(s4, o3), n5 = fmaxf(s5, o2), n6 = fmaxf(s6, o1), n7 = fmaxf(s7, o0);
        CSWAPD(n0, n4) CSWAPD(n1, n5) CSWAPD(n2, n6) CSWAPD(n3, n7)
        CSWAPD(n0, n2) CSWAPD(n1, n3) CSWAPD(n4, n6) CSWAPD(n5, n7)
        CSWAPD(n0, n1) CSWAPD(n2, n3) CSWAPD(n4, n5) CSWAPD(n6, n7)
        s0 = n0; s1 = n1; s2 = n2; s3 = n3; s4 = n4; s5 = n5; s6 = n6; s7 = n7;
    }
    const float T = s7;   // exact 8th-largest pd of row r

    // pass 2: collect indices with pd >= T
#pragma unroll 4
    for (int mm = 0; mm < 256; ++mm) {
        int m = (mm << 3) | part;
        float4 xm = xs[m];
        float dot = fmaf(xr.x, xm.x, fmaf(xr.y, xm.y, xr.z * xm.z));
        float pd = fmaf(2.f, dot, -(xr.w + xm.w));
        if (pd >= T) {
            int slot = atomicAdd(&cnt[lr], 1);
            if (slot < CAP_) lists[lr][slot] = m | ((pd > T) ? 0x10000 : 0);
        }
    }
    __syncthreads();

    // finalize selection: all strictly-greater, then smallest-index ties (lax.top_k stable)
    if (part == 0) {
        int c = cnt[lr]; if (c > CAP_) c = CAP_;
        int ng = 0;
        for (int q = 0; q < c; ++q) {
            int v = lists[lr][q];
            if (v & 0x10000) sel[lr][ng++] = v & 0xFFFF;
        }
        int prev = -1;
        while (ng < KNN_) {
            int best = 0x7FFFFFFF;
            for (int q = 0; q < c; ++q) {
                int v = lists[lr][q];
                if (!(v & 0x10000)) {
                    int m = v & 0xFFFF;
                    if (m > prev && m < best) best = m;
                }
            }
            if (best == 0x7FFFFFFF) best = r;   // pathological-overflow fallback
            sel[lr][ng++] = best; prev = best;
        }
    }
    __syncthreads();

    // fused edge-conv: each part handles one neighbor, max-reduce over the 8 lanes
    const int ms = sel[lr][part];
    const float4 fm = xs[ms];
    const float g0 = fm.x - xr.x, g1 = fm.y - xr.y, g2 = fm.z - xr.z;
    float h0 = eff[24], h1 = eff[25], h2 = eff[26];
    h0 = fmaf(g0, eff[0], h0);  h0 = fmaf(g1, eff[1], h0);  h0 = fmaf(g2, eff[2], h0);
    h0 = fmaf(xr.x, eff[3], h0); h0 = fmaf(xr.y, eff[4], h0); h0 = fmaf(xr.z, eff[5], h0);
    h1 = fmaf(g0, eff[6], h1);  h1 = fmaf(g1, eff[7], h1);  h1 = fmaf(g2, eff[8], h1);
    h1 = fmaf(xr.x, eff[9], h1); h1 = fmaf(xr.y, eff[10], h1); h1 = fmaf(xr.z, eff[11], h1);
    h2 = fmaf(g0, eff[12], h2); h2 = fmaf(g1, eff[13], h2); h2 = fmaf(g2, eff[14], h2);
    h2 = fmaf(xr.x, eff[15], h2); h2 = fmaf(xr.y, eff[16], h2); h2 = fmaf(xr.z, eff[17], h2);
#pragma unroll
    for (int w = 1; w < 8; w <<= 1) {
        h0 = fmaxf(h0, __shfl_xor(h0, w));
        h1 = fmaxf(h1, __shfl_xor(h1, w));
        h2 = fmaxf(h2, __shfl_xor(h2, w));
    }
    if (part == 0) {
        const float* bp = bias + (r & 63) * 3;
        float* op = out + (size_t)(bb * 2048 + r) * 3;
        op[0] = leaky(h0 + bp[0]);
        op[1] = leaky(h1 + bp[1]);
        op[2] = leaky(h2 + bp[2]);
    }
}

extern "C" void kernel_launch(void* const* d_in, const int* in_sizes, int n_in,
                              void* d_out, int out_size, void* d_ws, size_t ws_size,
                              hipStream_t stream)
{
    const float* t0 = (const float*)d_in[0];
    const float* t1 = (const float*)d_in[1];
    const float* t2 = (const float*)d_in[2];
    const float* t3 = (const float*)d_in[3];
    const float* t4 = (const float*)d_in[4];
    const float* t5 = (const float*)d_in[5];
    const float* Wr0 = (const float*)d_in[6];
    const float* Wr1 = (const float*)d_in[7];
    const float* Wr2 = (const float*)d_in[8];
    const float* Wr3 = (const float*)d_in[9];
    const float* Wr4 = (const float*)d_in[10];
    const float* Wr5 = (const float*)d_in[11];
    const float* Wb  = (const float*)d_in[12];
    const float* Wl1 = (const float*)d_in[13];
    const float* Wl2 = (const float*)d_in[14];
    const float* bias = (const float*)d_in[15];
    const float* c1w = (const float*)d_in[16];
    const float* c1b = (const float*)d_in[17];
    const float* c2w = (const float*)d_in[18];
    const float* c2b = (const float*)d_in[19];
    float* ws = (float*)d_ws;
    float* out = (float*)d_out;

    hipLaunchKernelGGL(kA, dim3(14), dim3(128), 0, stream,
                       t0, t1, t2, t3, t4, t5, Wr0, Wr1, Wr2, Wr3, Wr4, Wr5,
                       Wl1, Wl2, c1w, c1b, c2w, c2b, ws);
    hipLaunchKernelGGL(kB1, dim3(1024), dim3(256), 0, stream, t5, Wb, ws);
    hipLaunchKernelGGL(kB2, dim3(128), dim3(256), 0, stream, ws);
    hipLaunchKernelGGL(kC, dim3(1024), dim3(256), 0, stream, ws, bias, out);
}

// Round 2
// 354.027 us; speedup vs baseline: 1.0020x; 1.0020x over previous
//
#include <hip/hip_runtime.h>
#include <float.h>

// Problem constants
#define B_    16
#define NODE_ 32
#define DEG_  64
#define KNN_  8
#define ROWS_ 2048      // NODE*DEG

// ws layout (float offsets)
#define OFF_X     0                    // [16][2048] float4 (x0,x1,x2,xx)  = 131072 floats
#define OFF_Y     131072               // [16][32][8192]                    = 4194304 floats
#define OFF_ROOT  (OFF_Y + 4194304)    // [16][32][4]                       = 2048
#define OFF_WL12  (OFF_ROOT + 2048)    // [128][4]                          = 512
#define OFF_EFF   (OFF_WL12 + 512)     // [0..17]=Weff[3][6], [24..26]=beff = 32

__device__ __forceinline__ float med3f(float a, float b, float c) {
    return __builtin_amdgcn_fmed3f(a, b, c);
}
__device__ __forceinline__ float leaky(float v) { return v >= 0.f ? v : 0.2f * v; }

// ---------------- Kernel A: tiny precomputes (unchanged from R1) ----------------
__global__ __launch_bounds__(128) void kA(
    const float* __restrict__ t0, const float* __restrict__ t1, const float* __restrict__ t2,
    const float* __restrict__ t3, const float* __restrict__ t4, const float* __restrict__ t5,
    const float* __restrict__ Wr0, const float* __restrict__ Wr1, const float* __restrict__ Wr2,
    const float* __restrict__ Wr3, const float* __restrict__ Wr4, const float* __restrict__ Wr5,
    const float* __restrict__ Wl1, const float* __restrict__ Wl2,
    const float* __restrict__ c1w, const float* __restrict__ c1b,
    const float* __restrict__ c2w, const float* __restrict__ c2b,
    float* __restrict__ ws)
{
    const int blk = blockIdx.x, tid = threadIdx.x;
    if (blk == 0) {
        const float* wp = Wl1 + tid * 1280;
        float a0 = 0.f, a1 = 0.f, a2 = 0.f;
        for (int s = 0; s < 1280; ++s) {
            float w = wp[s];
            a0 = fmaf(w, Wl2[s * 3 + 0], a0);
            a1 = fmaf(w, Wl2[s * 3 + 1], a1);
            a2 = fmaf(w, Wl2[s * 3 + 2], a2);
        }
        float* o = ws + OFF_WL12 + tid * 4;
        o[0] = a0; o[1] = a1; o[2] = a2; o[3] = 0.f;
    } else if (blk <= 12) {
        int idx = (blk - 1) * 128 + tid;           // 0..1535
        int c = idx % 3, n = (idx / 3) & 31, b = idx / 96;
        float acc = 0.f;
#define TREE(T, W, RN, F) { \
        const float* tp = T + (b * RN + ((n * RN) >> 5)) * F; \
        for (int k = 0; k < F; ++k) acc = fmaf(tp[k], W[k * 3 + c], acc); }
        TREE(t0, Wr0, 1, 96)
        TREE(t1, Wr1, 2, 256)
        TREE(t2, Wr2, 4, 256)
        TREE(t3, Wr3, 8, 256)
        TREE(t4, Wr4, 16, 128)
        TREE(t5, Wr5, 32, 128)
#undef TREE
        ws[OFF_ROOT + (b * 32 + n) * 4 + c] = acc;
    } else {
        if (tid < 18) {
            int p = tid / 6, c = tid % 6;
            float a = 0.f;
            for (int o = 0; o < 64; ++o) a = fmaf(c2w[p * 64 + o], c1w[o * 6 + c], a);
            ws[OFF_EFF + tid] = a;
        } else if (tid < 21) {
            int p = tid - 18;
            float a = c2b[p];
            for (int o = 0; o < 64; ++o) a = fmaf(c2w[p * 64 + o], c1b[o], a);
            ws[OFF_EFF + 24 + p] = a;
        }
    }
}

// ---------------- Kernel B1: Y = leaky(t5 @ W_branch), float4 W loads ----------------
// grid 1024 = 32 n * 32 jt. block 256 = 64 j-quads * 4 b-quads.
// thread: j = jt*256 + (tid&63)*4 (4 consecutive j), b = 4*(tid>>6) .. +3
__global__ __launch_bounds__(256) void kB1(const float* __restrict__ t5,
                                           const float* __restrict__ Wb,
                                           float* __restrict__ ws)
{
    const int n = blockIdx.x >> 5, jt = blockIdx.x & 31, tid = threadIdx.x;
    __shared__ float ts[128 * 16];                 // [k][b]
    for (int q = tid; q < 2048; q += 256) {
        int b = q >> 7, k = q & 127;
        ts[k * 16 + b] = t5[b * 4096 + n * 128 + k];
    }
    __syncthreads();
    const int j  = jt * 256 + ((tid & 63) << 2);
    const int bq = tid >> 6;                       // 0..3  (uniform per wave)
    const float* wp = Wb + n * 1048576 + j;
    float4 acc0 = {0,0,0,0}, acc1 = {0,0,0,0}, acc2 = {0,0,0,0}, acc3 = {0,0,0,0};
#pragma unroll 4
    for (int k = 0; k < 128; ++k) {
        float4 wv = *(const float4*)(wp + k * 8192);
        float4 tb = *(const float4*)(ts + k * 16 + bq * 4);   // wave-uniform broadcast
        acc0.x = fmaf(tb.x, wv.x, acc0.x); acc0.y = fmaf(tb.x, wv.y, acc0.y);
        acc0.z = fmaf(tb.x, wv.z, acc0.z); acc0.w = fmaf(tb.x, wv.w, acc0.w);
        acc1.x = fmaf(tb.y, wv.x, acc1.x); acc1.y = fmaf(tb.y, wv.y, acc1.y);
        acc1.z = fmaf(tb.y, wv.z, acc1.z); acc1.w = fmaf(tb.y, wv.w, acc1.w);
        acc2.x = fmaf(tb.z, wv.x, acc2.x); acc2.y = fmaf(tb.z, wv.y, acc2.y);
        acc2.z = fmaf(tb.z, wv.z, acc2.z); acc2.w = fmaf(tb.z, wv.w, acc2.w);
        acc3.x = fmaf(tb.w, wv.x, acc3.x); acc3.y = fmaf(tb.w, wv.y, acc3.y);
        acc3.z = fmaf(tb.w, wv.z, acc3.z); acc3.w = fmaf(tb.w, wv.w, acc3.w);
    }
    float* yb = ws + OFF_Y + n * 8192 + j;
#define STY(A, BI) { float4 y = make_float4(leaky(A.x), leaky(A.y), leaky(A.z), leaky(A.w)); \
                     *(float4*)(yb + (size_t)(4 * bq + BI) * 262144) = y; }
    STY(acc0, 0) STY(acc1, 1) STY(acc2, 2) STY(acc3, 3)
#undef STY
}

// ---------------- Kernel B2: x = root + Y @ Wl12, pack (x0,x1,x2,xx) ----------------
__global__ __launch_bounds__(256) void kB2(float* __restrict__ ws)
{
    __shared__ float wl[512];
    const int tid = threadIdx.x;
    for (int q = tid; q < 512; q += 256) wl[q] = ws[OFF_WL12 + q];
    __syncthreads();
    const int gid = blockIdx.x * 256 + tid;
    const int b = gid >> 11, r = gid & 2047, n = r >> 6;
    const float* rt = ws + OFF_ROOT + ((b * 32 + n) << 2);
    float x0 = rt[0], x1 = rt[1], x2 = rt[2];
    const float4* yp = (const float4*)(ws + OFF_Y + (size_t)(b * 32 + n) * 8192 + ((r & 63) << 7));
#pragma unroll 8
    for (int i4 = 0; i4 < 32; ++i4) {
        float4 y = yp[i4];
        const float4* wr = ((const float4*)wl) + (i4 << 2);
        float4 w0 = wr[0], w1 = wr[1], w2 = wr[2], w3 = wr[3];
        x0 = fmaf(y.x, w0.x, x0); x0 = fmaf(y.y, w1.x, x0); x0 = fmaf(y.z, w2.x, x0); x0 = fmaf(y.w, w3.x, x0);
        x1 = fmaf(y.x, w0.y, x1); x1 = fmaf(y.y, w1.y, x1); x1 = fmaf(y.z, w2.y, x1); x1 = fmaf(y.w, w3.y, x1);
        x2 = fmaf(y.x, w0.z, x2); x2 = fmaf(y.y, w1.z, x2); x2 = fmaf(y.z, w2.z, x2); x2 = fmaf(y.w, w3.z, x2);
    }
    float xx = fmaf(x0, x0, fmaf(x1, x1, x2 * x2));
    ((float4*)(ws + OFF_X))[gid] = make_float4(x0, x1, x2, xx);
}

// ---------------- Kernel C: exact knn top-8 + fused edge-conv ----------------
// grid 1024 = 16 b * 64 rowtiles(32 rows), block 256.
// Pass1/2: 8 row-groups (4 rows each) x 32 m-parts -> each xs read reused 4x.
#define CAP_ 16
#define CSWAPD(a, b) { float _hi = fmaxf(a, b), _lo = fminf(a, b); a = _hi; b = _lo; }
#define INS8(P, s0,s1,s2,s3,s4,s5,s6,s7) \
    s7 = med3f(P, s7, s6); s6 = med3f(P, s6, s5); \
    s5 = med3f(P, s5, s4); s4 = med3f(P, s4, s3); \
    s3 = med3f(P, s3, s2); s2 = med3f(P, s2, s1); \
    s1 = med3f(P, s1, s0); s0 = fmaxf(s0, P);
#define MERGE8(W, s0,s1,s2,s3,s4,s5,s6,s7) { \
    float o0 = __shfl_xor(s0, W), o1 = __shfl_xor(s1, W), o2 = __shfl_xor(s2, W), o3 = __shfl_xor(s3, W); \
    float o4 = __shfl_xor(s4, W), o5 = __shfl_xor(s5, W), o6 = __shfl_xor(s6, W), o7 = __shfl_xor(s7, W); \
    float n0 = fmaxf(s0, o7), n1 = fmaxf(s1, o6), n2 = fmaxf(s2, o5), n3 = fmaxf(s3, o4); \
    float n4 = fmaxf(s4, o3), n5 = fmaxf(s5, o2), n6 = fmaxf(s6, o1), n7 = fmaxf(s7, o0); \
    CSWAPD(n0, n4) CSWAPD(n1, n5) CSWAPD(n2, n6) CSWAPD(n3, n7) \
    CSWAPD(n0, n2) CSWAPD(n1, n3) CSWAPD(n4, n6) CSWAPD(n5, n7) \
    CSWAPD(n0, n1) CSWAPD(n2, n3) CSWAPD(n4, n5) CSWAPD(n6, n7) \
    s0 = n0; s1 = n1; s2 = n2; s3 = n3; s4 = n4; s5 = n5; s6 = n6; s7 = n7; }
#define PD(XR, XM) fmaf(2.f, fmaf(XR.x, XM.x, fmaf(XR.y, XM.y, XR.z * XM.z)), -(XR.w + XM.w))

__global__ __launch_bounds__(256) void kC(const float* __restrict__ ws,
                                          const float* __restrict__ bias,
                                          float* __restrict__ out)
{
    const int bb = blockIdx.x >> 6, rtile = blockIdx.x & 63, tid = threadIdx.x;
    __shared__ float4 xs[2048];
    __shared__ float eff[32];
    __shared__ int cnt[32];
    __shared__ int lists[32][CAP_];
    __shared__ int sel[32][KNN_];

    const float4* xg = (const float4*)(ws + OFF_X) + bb * 2048;
    for (int q = tid; q < 2048; q += 256) xs[q] = xg[q];
    if (tid < 32) { eff[tid] = ws[OFF_EFF + tid]; cnt[tid] = 0; }
    __syncthreads();

    const int g  = tid >> 5;          // row-group 0..7 (4 rows)
    const int mp = tid & 31;          // m-part (m = mm*32 + mp)
    const int r0 = rtile * 32 + g * 4;
    const float4 xa = xs[r0], xb = xs[r0 + 1], xc = xs[r0 + 2], xd = xs[r0 + 3];

    float A0=-FLT_MAX,A1=-FLT_MAX,A2=-FLT_MAX,A3=-FLT_MAX,A4=-FLT_MAX,A5=-FLT_MAX,A6=-FLT_MAX,A7=-FLT_MAX;
    float B0=-FLT_MAX,B1=-FLT_MAX,B2=-FLT_MAX,B3=-FLT_MAX,B4=-FLT_MAX,B5=-FLT_MAX,B6=-FLT_MAX,B7=-FLT_MAX;
    float C0=-FLT_MAX,C1=-FLT_MAX,C2=-FLT_MAX,C3=-FLT_MAX,C4=-FLT_MAX,C5=-FLT_MAX,C6=-FLT_MAX,C7=-FLT_MAX;
    float D0=-FLT_MAX,D1=-FLT_MAX,D2=-FLT_MAX,D3=-FLT_MAX,D4=-FLT_MAX,D5=-FLT_MAX,D6=-FLT_MAX,D7=-FLT_MAX;

    // pass 1: top-8 values, 4 rows per xs read
#pragma unroll 4
    for (int mm = 0; mm < 64; ++mm) {
        float4 xm = xs[(mm << 5) | mp];
        float pa = PD(xa, xm); INS8(pa, A0,A1,A2,A3,A4,A5,A6,A7)
        float pb = PD(xb, xm); INS8(pb, B0,B1,B2,B3,B4,B5,B6,B7)
        float pc = PD(xc, xm); INS8(pc, C0,C1,C2,C3,C4,C5,C6,C7)
        float pdv = PD(xd, xm); INS8(pdv, D0,D1,D2,D3,D4,D5,D6,D7)
    }
    // merge across the 32 m-parts (contiguous aligned 32-lane group)
#pragma unroll
    for (int w = 1; w < 32; w <<= 1) {
        MERGE8(w, A0,A1,A2,A3,A4,A5,A6,A7)
        MERGE8(w, B0,B1,B2,B3,B4,B5,B6,B7)
        MERGE8(w, C0,C1,C2,C3,C4,C5,C6,C7)
        MERGE8(w, D0,D1,D2,D3,D4,D5,D6,D7)
    }
    const float Ta = A7, Tb = B7, Tc = C7, Td = D7;   // exact 8th-largest per row

    // pass 2: collect indices with pd >= T
#pragma unroll 4
    for (int mm = 0; mm < 64; ++mm) {
        int m = (mm << 5) | mp;
        float4 xm = xs[m];
        float pa = PD(xa, xm);
        float pb = PD(xb, xm);
        float pc = PD(xc, xm);
        float pdv = PD(xd, xm);
        if (pa >= Ta) { int s = atomicAdd(&cnt[g*4+0], 1); if (s < CAP_) lists[g*4+0][s] = m | ((pa > Ta) ? 0x10000 : 0); }
        if (pb >= Tb) { int s = atomicAdd(&cnt[g*4+1], 1); if (s < CAP_) lists[g*4+1][s] = m | ((pb > Tb) ? 0x10000 : 0); }
        if (pc >= Tc) { int s = atomicAdd(&cnt[g*4+2], 1); if (s < CAP_) lists[g*4+2][s] = m | ((pc > Tc) ? 0x10000 : 0); }
        if (pdv >= Td){ int s = atomicAdd(&cnt[g*4+3], 1); if (s < CAP_) lists[g*4+3][s] = m | ((pdv > Td) ? 0x10000 : 0); }
    }
    __syncthreads();

    // finalize: strictly-greater first, then smallest-index ties (lax.top_k semantics)
    const int lr = tid >> 3;
    const int part = tid & 7;
    const int r = rtile * 32 + lr;
    if (part == 0) {
        int c = cnt[lr]; if (c > CAP_) c = CAP_;
        int ng = 0;
        for (int q = 0; q < c; ++q) {
            int v = lists[lr][q];
            if (v & 0x10000) sel[lr][ng++] = v & 0xFFFF;
        }
        int prev = -1;
        while (ng < KNN_) {
            int best = 0x7FFFFFFF;
            for (int q = 0; q < c; ++q) {
                int v = lists[lr][q];
                if (!(v & 0x10000)) {
                    int m = v & 0xFFFF;
                    if (m > prev && m < best) best = m;
                }
            }
            if (best == 0x7FFFFFFF) best = r;
            sel[lr][ng++] = best; prev = best;
        }
    }
    __syncthreads();

    // fused edge-conv: one neighbor per part, max-reduce over 8 lanes
    const float4 xr = xs[r];
    const int ms = sel[lr][part];
    const float4 fm = xs[ms];
    const float g0 = fm.x - xr.x, g1 = fm.y - xr.y, g2 = fm.z - xr.z;
    float h0 = eff[24], h1 = eff[25], h2 = eff[26];
    h0 = fmaf(g0, eff[0], h0);  h0 = fmaf(g1, eff[1], h0);  h0 = fmaf(g2, eff[2], h0);
    h0 = fmaf(xr.x, eff[3], h0); h0 = fmaf(xr.y, eff[4], h0); h0 = fmaf(xr.z, eff[5], h0);
    h1 = fmaf(g0, eff[6], h1);  h1 = fmaf(g1, eff[7], h1);  h1 = fmaf(g2, eff[8], h1);
    h1 = fmaf(xr.x, eff[9], h1); h1 = fmaf(xr.y, eff[10], h1); h1 = fmaf(xr.z, eff[11], h1);
    h2 = fmaf(g0, eff[12], h2); h2 = fmaf(g1, eff[13], h2); h2 = fmaf(g2, eff[14], h2);
    h2 = fmaf(xr.x, eff[15], h2); h2 = fmaf(xr.y, eff[16], h2); h2 = fmaf(xr.z, eff[17], h2);
#pragma unroll
    for (int w = 1; w < 8; w <<= 1) {
        h0 = fmaxf(h0, __shfl_xor(h0, w));
        h1 = fmaxf(h1, __shfl_xor(h1, w));
        h2 = fmaxf(h2, __shfl_xor(h2, w));
    }
    if (part == 0) {
        const float* bp = bias + (r & 63) * 3;
        float* op = out + (size_t)(bb * 2048 + r) * 3;
        op[0] = leaky(h0 + bp[0]);
        op[1] = leaky(h1 + bp[1]);
        op[2] = leaky(h2 + bp[2]);
    }
}

extern "C" void kernel_launch(void* const* d_in, const int* in_sizes, int n_in,
                              void* d_out, int out_size, void* d_ws, size_t ws_size,
                              hipStream_t stream)
{
    const float* t0 = (const float*)d_in[0];
    const float* t1 = (const float*)d_in[1];
    const float* t2 = (const float*)d_in[2];
    const float* t3 = (const float*)d_in[3];
    const float* t4 = (const float*)d_in[4];
    const float* t5 = (const float*)d_in[5];
    const float* Wr0 = (const float*)d_in[6];
    const float* Wr1 = (const float*)d_in[7];
    const float* Wr2 = (const float*)d_in[8];
    const float* Wr3 = (const float*)d_in[9];
    const float* Wr4 = (const float*)d_in[10];
    const float* Wr5 = (const float*)d_in[11];
    const float* Wb  = (const float*)d_in[12];
    const float* Wl1 = (const float*)d_in[13];
    const float* Wl2 = (const float*)d_in[14];
    const float* bias = (const float*)d_in[15];
    const float* c1w = (const float*)d_in[16];
    const float* c1b = (const float*)d_in[17];
    const float* c2w = (const float*)d_in[18];
    const float* c2b = (const float*)d_in[19];
    float* ws = (float*)d_ws;
    float* out = (float*)d_out;

    hipLaunchKernelGGL(kA, dim3(14), dim3(128), 0, stream,
                       t0, t1, t2, t3, t4, t5, Wr0, Wr1, Wr2, Wr3, Wr4, Wr5,
                       Wl1, Wl2, c1w, c1b, c2w, c2b, ws);
    hipLaunchKernelGGL(kB1, dim3(1024), dim3(256), 0, stream, t5, Wb, ws);
    hipLaunchKernelGGL(kB2, dim3(128), dim3(256), 0, stream, ws);
    hipLaunchKernelGGL(kC, dim3(1024), dim3(256), 0, stream, ws, bias, out);
}

// Round 3
// 326.051 us; speedup vs baseline: 1.0879x; 1.0858x over previous
//
#include <hip/hip_runtime.h>
#include <float.h>

// Problem constants
#define B_    16
#define NODE_ 32
#define DEG_  64
#define KNN_  8
#define ROWS_ 2048      // NODE*DEG

// ws layout (float offsets) — Y eliminated
#define OFF_X     0                    // [16][2048] float4 (x0,x1,x2,xx) = 131072 floats
#define OFF_ROOT  131072               // [16][32][4]                      = 2048
#define OFF_WL12  (OFF_ROOT + 2048)    // [128][4]                         = 512
#define OFF_EFF   (OFF_WL12 + 512)     // [0..17]=Weff[3][6], [24..26]=beff

__device__ __forceinline__ float med3f(float a, float b, float c) {
    return __builtin_amdgcn_fmed3f(a, b, c);
}
__device__ __forceinline__ float leaky(float v) { return v >= 0.f ? v : 0.2f * v; }

// ---------------- Kernel A: precomputes (coalesced Wl12) ----------------
// grid 15 x 256: blk 0..7 Wl12 (wave-per-row), 8..13 root, 14 eff
__global__ __launch_bounds__(256) void kA(
    const float* __restrict__ t0, const float* __restrict__ t1, const float* __restrict__ t2,
    const float* __restrict__ t3, const float* __restrict__ t4, const float* __restrict__ t5,
    const float* __restrict__ Wr0, const float* __restrict__ Wr1, const float* __restrict__ Wr2,
    const float* __restrict__ Wr3, const float* __restrict__ Wr4, const float* __restrict__ Wr5,
    const float* __restrict__ Wl1, const float* __restrict__ Wl2,
    const float* __restrict__ c1w, const float* __restrict__ c1b,
    const float* __restrict__ c2w, const float* __restrict__ c2b,
    float* __restrict__ ws)
{
    const int blk = blockIdx.x, tid = threadIdx.x;
    if (blk < 8) {
        // Wl12[i][c] = sum_s Wl1[i,s]*Wl2[s,c]; wave per row, lanes over s
        const int lane = tid & 63;
        const int ibase = blk * 16 + (tid >> 6) * 4;
#pragma unroll
        for (int ii = 0; ii < 4; ++ii) {
            const float* wp = Wl1 + (size_t)(ibase + ii) * 1280;
            float a0 = 0.f, a1 = 0.f, a2 = 0.f;
            for (int s5 = 0; s5 < 20; ++s5) {
                int s = s5 * 64 + lane;
                float w = wp[s];
                a0 = fmaf(w, Wl2[s * 3 + 0], a0);
                a1 = fmaf(w, Wl2[s * 3 + 1], a1);
                a2 = fmaf(w, Wl2[s * 3 + 2], a2);
            }
#pragma unroll
            for (int d = 1; d < 64; d <<= 1) {
                a0 += __shfl_xor(a0, d);
                a1 += __shfl_xor(a1, d);
                a2 += __shfl_xor(a2, d);
            }
            if (lane == 0) {
                float* o = ws + OFF_WL12 + (ibase + ii) * 4;
                o[0] = a0; o[1] = a1; o[2] = a2; o[3] = 0.f;
            }
        }
    } else if (blk < 14) {
        int idx = (blk - 8) * 256 + tid;           // 0..1535
        int c = idx % 3, n = (idx / 3) & 31, b = idx / 96;
        float acc = 0.f;
#define TREE(T, W, RN, F) { \
        const float* tp = T + (b * RN + ((n * RN) >> 5)) * F; \
        for (int k = 0; k < F; ++k) acc = fmaf(tp[k], W[k * 3 + c], acc); }
        TREE(t0, Wr0, 1, 96)
        TREE(t1, Wr1, 2, 256)
        TREE(t2, Wr2, 4, 256)
        TREE(t3, Wr3, 8, 256)
        TREE(t4, Wr4, 16, 128)
        TREE(t5, Wr5, 32, 128)
#undef TREE
        ws[OFF_ROOT + (b * 32 + n) * 4 + c] = acc;
    } else {
        if (tid < 18) {
            int p = tid / 6, c = tid % 6;
            float a = 0.f;
            for (int o = 0; o < 64; ++o) a = fmaf(c2w[p * 64 + o], c1w[o * 6 + c], a);
            ws[OFF_EFF + tid] = a;
        } else if (tid < 21) {
            int p = tid - 18;
            float a = c2b[p];
            for (int o = 0; o < 64; ++o) a = fmaf(c2w[p * 64 + o], c1b[o], a);
            ws[OFF_EFF + 24 + p] = a;
        }
    }
}

// ---------------- Kernel BX: x = root + leaky(t5@Wb) @ Wl12, pack X ----------------
// grid 512 = 32 n * 16 jt; block 256 = 4 waves; wave w owns d = jt*4+w (full
// 128-wide i-reduction stays inside the wave). lane: 2 consecutive j (float2 W).
__global__ __launch_bounds__(256) void kBX(const float* __restrict__ t5,
                                           const float* __restrict__ Wb,
                                           float* __restrict__ ws)
{
    const int n = blockIdx.x >> 4, jt = blockIdx.x & 15, tid = threadIdx.x;
    __shared__ float ts[2048];                     // [k][b]
    for (int q = tid; q < 2048; q += 256) {
        int b = q >> 7, k = q & 127;
        ts[k * 16 + b] = t5[b * 4096 + n * 128 + k];
    }
    __syncthreads();
    const int w = tid >> 6, lane = tid & 63;
    const int d = jt * 4 + w;
    const int i0 = lane * 2;
    const float* wp = Wb + (size_t)n * 1048576 + d * 128 + i0;

    float acc[16][2];
#pragma unroll
    for (int b = 0; b < 16; ++b) { acc[b][0] = 0.f; acc[b][1] = 0.f; }

#pragma unroll 4
    for (int k = 0; k < 128; ++k) {
        float2 wv = *(const float2*)(wp + (size_t)k * 8192);
        const float4* tk = (const float4*)(ts + (k << 4));
        float4 t0v = tk[0], t1v = tk[1], t2v = tk[2], t3v = tk[3];
#define FM(BI, TV) acc[BI][0] = fmaf(TV, wv.x, acc[BI][0]); acc[BI][1] = fmaf(TV, wv.y, acc[BI][1]);
        FM(0, t0v.x) FM(1, t0v.y) FM(2, t0v.z) FM(3, t0v.w)
        FM(4, t1v.x) FM(5, t1v.y) FM(6, t1v.z) FM(7, t1v.w)
        FM(8, t2v.x) FM(9, t2v.y) FM(10, t2v.z) FM(11, t2v.w)
        FM(12, t3v.x) FM(13, t3v.y) FM(14, t3v.z) FM(15, t3v.w)
#undef FM
    }

    // epilogue: contract i -> 3 cols, reduce across the wave's 64 lanes
    const float4 wl0 = *(const float4*)(ws + OFF_WL12 + i0 * 4);
    const float4 wl1 = *(const float4*)(ws + OFF_WL12 + (i0 + 1) * 4);
    float P[16][3];
#pragma unroll
    for (int b = 0; b < 16; ++b) {
        float y0 = leaky(acc[b][0]), y1 = leaky(acc[b][1]);
        P[b][0] = fmaf(y1, wl1.x, y0 * wl0.x);
        P[b][1] = fmaf(y1, wl1.y, y0 * wl0.y);
        P[b][2] = fmaf(y1, wl1.z, y0 * wl0.z);
    }
#pragma unroll
    for (int b = 0; b < 16; ++b) {
#pragma unroll
        for (int dd = 1; dd < 64; dd <<= 1) {
            P[b][0] += __shfl_xor(P[b][0], dd);
            P[b][1] += __shfl_xor(P[b][1], dd);
            P[b][2] += __shfl_xor(P[b][2], dd);
        }
    }
    // lane b takes batch b's sums (branchless select, all-static reg indices)
    float q0 = P[0][0], q1 = P[0][1], q2 = P[0][2];
#pragma unroll
    for (int b = 1; b < 16; ++b) {
        bool m = (lane == b);
        q0 = m ? P[b][0] : q0;
        q1 = m ? P[b][1] : q1;
        q2 = m ? P[b][2] : q2;
    }
    if (lane < 16) {
        float4 rt = ((const float4*)(ws + OFF_ROOT))[lane * 32 + n];
        float x0 = rt.x + q0, x1 = rt.y + q1, x2 = rt.z + q2;
        float xx = fmaf(x0, x0, fmaf(x1, x1, x2 * x2));
        ((float4*)(ws + OFF_X))[lane * 2048 + n * 64 + d] = make_float4(x0, x1, x2, xx);
    }
}

// ---------------- Kernel C: exact knn top-8 + fused edge-conv ----------------
// grid 1024 = 16 b * 64 rowtiles(32 rows), block 256.
// Pass1/2: 8 row-groups (4 rows each) x 32 m-parts -> each xs read reused 4x.
#define CAP_ 16
#define CSWAPD(a, b) { float _hi = fmaxf(a, b), _lo = fminf(a, b); a = _hi; b = _lo; }
#define INS8(P, s0,s1,s2,s3,s4,s5,s6,s7) \
    s7 = med3f(P, s7, s6); s6 = med3f(P, s6, s5); \
    s5 = med3f(P, s5, s4); s4 = med3f(P, s4, s3); \
    s3 = med3f(P, s3, s2); s2 = med3f(P, s2, s1); \
    s1 = med3f(P, s1, s0); s0 = fmaxf(s0, P);
#define MERGE8(W, s0,s1,s2,s3,s4,s5,s6,s7) { \
    float o0 = __shfl_xor(s0, W), o1 = __shfl_xor(s1, W), o2 = __shfl_xor(s2, W), o3 = __shfl_xor(s3, W); \
    float o4 = __shfl_xor(s4, W), o5 = __shfl_xor(s5, W), o6 = __shfl_xor(s6, W), o7 = __shfl_xor(s7, W); \
    float n0 = fmaxf(s0, o7), n1 = fmaxf(s1, o6), n2 = fmaxf(s2, o5), n3 = fmaxf(s3, o4); \
    float n4 = fmaxf(s4, o3), n5 = fmaxf(s5, o2), n6 = fmaxf(s6, o1), n7 = fmaxf(s7, o0); \
    CSWAPD(n0, n4) CSWAPD(n1, n5) CSWAPD(n2, n6) CSWAPD(n3, n7) \
    CSWAPD(n0, n2) CSWAPD(n1, n3) CSWAPD(n4, n6) CSWAPD(n5, n7) \
    CSWAPD(n0, n1) CSWAPD(n2, n3) CSWAPD(n4, n5) CSWAPD(n6, n7) \
    s0 = n0; s1 = n1; s2 = n2; s3 = n3; s4 = n4; s5 = n5; s6 = n6; s7 = n7; }
#define PD(XR, XM) fmaf(2.f, fmaf(XR.x, XM.x, fmaf(XR.y, XM.y, XR.z * XM.z)), -(XR.w + XM.w))

__global__ __launch_bounds__(256) void kC(const float* __restrict__ ws,
                                          const float* __restrict__ bias,
                                          float* __restrict__ out)
{
    const int bb = blockIdx.x >> 6, rtile = blockIdx.x & 63, tid = threadIdx.x;
    __shared__ float4 xs[2048];
    __shared__ float eff[32];
    __shared__ int cnt[32];
    __shared__ int lists[32][CAP_];
    __shared__ int sel[32][KNN_];

    const float4* xg = (const float4*)(ws + OFF_X) + bb * 2048;
    for (int q = tid; q < 2048; q += 256) xs[q] = xg[q];
    if (tid < 32) { eff[tid] = ws[OFF_EFF + tid]; cnt[tid] = 0; }
    __syncthreads();

    const int g  = tid >> 5;          // row-group 0..7 (4 rows)
    const int mp = tid & 31;          // m-part (m = mm*32 + mp)
    const int r0 = rtile * 32 + g * 4;
    const float4 xa = xs[r0], xb = xs[r0 + 1], xc = xs[r0 + 2], xd = xs[r0 + 3];

    float A0=-FLT_MAX,A1=-FLT_MAX,A2=-FLT_MAX,A3=-FLT_MAX,A4=-FLT_MAX,A5=-FLT_MAX,A6=-FLT_MAX,A7=-FLT_MAX;
    float B0=-FLT_MAX,B1=-FLT_MAX,B2=-FLT_MAX,B3=-FLT_MAX,B4=-FLT_MAX,B5=-FLT_MAX,B6=-FLT_MAX,B7=-FLT_MAX;
    float C0=-FLT_MAX,C1=-FLT_MAX,C2=-FLT_MAX,C3=-FLT_MAX,C4=-FLT_MAX,C5=-FLT_MAX,C6=-FLT_MAX,C7=-FLT_MAX;
    float D0=-FLT_MAX,D1=-FLT_MAX,D2=-FLT_MAX,D3=-FLT_MAX,D4=-FLT_MAX,D5=-FLT_MAX,D6=-FLT_MAX,D7=-FLT_MAX;

#pragma unroll 4
    for (int mm = 0; mm < 64; ++mm) {
        float4 xm = xs[(mm << 5) | mp];
        float pa = PD(xa, xm); INS8(pa, A0,A1,A2,A3,A4,A5,A6,A7)
        float pb = PD(xb, xm); INS8(pb, B0,B1,B2,B3,B4,B5,B6,B7)
        float pc = PD(xc, xm); INS8(pc, C0,C1,C2,C3,C4,C5,C6,C7)
        float pdv = PD(xd, xm); INS8(pdv, D0,D1,D2,D3,D4,D5,D6,D7)
    }
#pragma unroll
    for (int w = 1; w < 32; w <<= 1) {
        MERGE8(w, A0,A1,A2,A3,A4,A5,A6,A7)
        MERGE8(w, B0,B1,B2,B3,B4,B5,B6,B7)
        MERGE8(w, C0,C1,C2,C3,C4,C5,C6,C7)
        MERGE8(w, D0,D1,D2,D3,D4,D5,D6,D7)
    }
    const float Ta = A7, Tb = B7, Tc = C7, Td = D7;   // exact 8th-largest per row

#pragma unroll 4
    for (int mm = 0; mm < 64; ++mm) {
        int m = (mm << 5) | mp;
        float4 xm = xs[m];
        float pa = PD(xa, xm);
        float pb = PD(xb, xm);
        float pc = PD(xc, xm);
        float pdv = PD(xd, xm);
        if (pa >= Ta) { int s = atomicAdd(&cnt[g*4+0], 1); if (s < CAP_) lists[g*4+0][s] = m | ((pa > Ta) ? 0x10000 : 0); }
        if (pb >= Tb) { int s = atomicAdd(&cnt[g*4+1], 1); if (s < CAP_) lists[g*4+1][s] = m | ((pb > Tb) ? 0x10000 : 0); }
        if (pc >= Tc) { int s = atomicAdd(&cnt[g*4+2], 1); if (s < CAP_) lists[g*4+2][s] = m | ((pc > Tc) ? 0x10000 : 0); }
        if (pdv >= Td){ int s = atomicAdd(&cnt[g*4+3], 1); if (s < CAP_) lists[g*4+3][s] = m | ((pdv > Td) ? 0x10000 : 0); }
    }
    __syncthreads();

    const int lr = tid >> 3;
    const int part = tid & 7;
    const int r = rtile * 32 + lr;
    if (part == 0) {
        int c = cnt[lr]; if (c > CAP_) c = CAP_;
        int ng = 0;
        for (int q = 0; q < c; ++q) {
            int v = lists[lr][q];
            if (v & 0x10000) sel[lr][ng++] = v & 0xFFFF;
        }
        int prev = -1;
        while (ng < KNN_) {
            int best = 0x7FFFFFFF;
            for (int q = 0; q < c; ++q) {
                int v = lists[lr][q];
                if (!(v & 0x10000)) {
                    int m = v & 0xFFFF;
                    if (m > prev && m < best) best = m;
                }
            }
            if (best == 0x7FFFFFFF) best = r;
            sel[lr][ng++] = best; prev = best;
        }
    }
    __syncthreads();

    const float4 xr = xs[r];
    const int ms = sel[lr][part];
    const float4 fm = xs[ms];
    const float g0 = fm.x - xr.x, g1 = fm.y - xr.y, g2 = fm.z - xr.z;
    float h0 = eff[24], h1 = eff[25], h2 = eff[26];
    h0 = fmaf(g0, eff[0], h0);  h0 = fmaf(g1, eff[1], h0);  h0 = fmaf(g2, eff[2], h0);
    h0 = fmaf(xr.x, eff[3], h0); h0 = fmaf(xr.y, eff[4], h0); h0 = fmaf(xr.z, eff[5], h0);
    h1 = fmaf(g0, eff[6], h1);  h1 = fmaf(g1, eff[7], h1);  h1 = fmaf(g2, eff[8], h1);
    h1 = fmaf(xr.x, eff[9], h1); h1 = fmaf(xr.y, eff[10], h1); h1 = fmaf(xr.z, eff[11], h1);
    h2 = fmaf(g0, eff[12], h2); h2 = fmaf(g1, eff[13], h2); h2 = fmaf(g2, eff[14], h2);
    h2 = fmaf(xr.x, eff[15], h2); h2 = fmaf(xr.y, eff[16], h2); h2 = fmaf(xr.z, eff[17], h2);
#pragma unroll
    for (int w = 1; w < 8; w <<= 1) {
        h0 = fmaxf(h0, __shfl_xor(h0, w));
        h1 = fmaxf(h1, __shfl_xor(h1, w));
        h2 = fmaxf(h2, __shfl_xor(h2, w));
    }
    if (part == 0) {
        const float* bp = bias + (r & 63) * 3;
        float* op = out + (size_t)(bb * 2048 + r) * 3;
        op[0] = leaky(h0 + bp[0]);
        op[1] = leaky(h1 + bp[1]);
        op[2] = leaky(h2 + bp[2]);
    }
}

extern "C" void kernel_launch(void* const* d_in, const int* in_sizes, int n_in,
                              void* d_out, int out_size, void* d_ws, size_t ws_size,
                              hipStream_t stream)
{
    const float* t0 = (const float*)d_in[0];
    const float* t1 = (const float*)d_in[1];
    const float* t2 = (const float*)d_in[2];
    const float* t3 = (const float*)d_in[3];
    const float* t4 = (const float*)d_in[4];
    const float* t5 = (const float*)d_in[5];
    const float* Wr0 = (const float*)d_in[6];
    const float* Wr1 = (const float*)d_in[7];
    const float* Wr2 = (const float*)d_in[8];
    const float* Wr3 = (const float*)d_in[9];
    const float* Wr4 = (const float*)d_in[10];
    const float* Wr5 = (const float*)d_in[11];
    const float* Wb  = (const float*)d_in[12];
    const float* Wl1 = (const float*)d_in[13];
    const float* Wl2 = (const float*)d_in[14];
    const float* bias = (const float*)d_in[15];
    const float* c1w = (const float*)d_in[16];
    const float* c1b = (const float*)d_in[17];
    const float* c2w = (const float*)d_in[18];
    const float* c2b = (const float*)d_in[19];
    float* ws = (float*)d_ws;
    float* out = (float*)d_out;

    hipLaunchKernelGGL(kA, dim3(15), dim3(256), 0, stream,
                       t0, t1, t2, t3, t4, t5, Wr0, Wr1, Wr2, Wr3, Wr4, Wr5,
                       Wl1, Wl2, c1w, c1b, c2w, c2b, ws);
    hipLaunchKernelGGL(kBX, dim3(512), dim3(256), 0, stream, t5, Wb, ws);
    hipLaunchKernelGGL(kC, dim3(1024), dim3(256), 0, stream, ws, bias, out);
}

// Round 4
// 284.903 us; speedup vs baseline: 1.2451x; 1.1444x over previous
//
#include <hip/hip_runtime.h>
#include <float.h>

// Problem constants
#define B_    16
#define NODE_ 32
#define DEG_  64
#define KNN_  8
#define ROWS_ 2048      // NODE*DEG

// ws layout (float offsets) — X.w holds 0.5*|x|^2 (rank statistic; edge-conv never uses it)
#define OFF_X     0                    // [16][2048] float4 (x0,x1,x2,xx/2) = 131072 floats
#define OFF_ROOT  131072               // [16][32][4]                        = 2048
#define OFF_WL12  (OFF_ROOT + 2048)    // [128][4]                           = 512
#define OFF_EFF   (OFF_WL12 + 512)     // [0..17]=Weff[3][6], [24..26]=beff

__device__ __forceinline__ float med3f(float a, float b, float c) {
    return __builtin_amdgcn_fmed3f(a, b, c);
}
__device__ __forceinline__ float leaky(float v) { return v >= 0.f ? v : 0.2f * v; }

// ---------------- Kernel A: precomputes, wave-parallel ----------------
// grid 161 x 256: blk 0..31 Wl12 (wave-per-row), 32..159 root (wave-per-(b,n)), 160 eff
__global__ __launch_bounds__(256) void kA(
    const float* __restrict__ t0, const float* __restrict__ t1, const float* __restrict__ t2,
    const float* __restrict__ t3, const float* __restrict__ t4, const float* __restrict__ t5,
    const float* __restrict__ Wr0, const float* __restrict__ Wr1, const float* __restrict__ Wr2,
    const float* __restrict__ Wr3, const float* __restrict__ Wr4, const float* __restrict__ Wr5,
    const float* __restrict__ Wl1, const float* __restrict__ Wl2,
    const float* __restrict__ c1w, const float* __restrict__ c1b,
    const float* __restrict__ c2w, const float* __restrict__ c2b,
    float* __restrict__ ws)
{
    const int blk = blockIdx.x, tid = threadIdx.x;
    const int w = tid >> 6, lane = tid & 63;
    if (blk < 32) {
        // Wl12[i][c] = sum_s Wl1[i,s]*Wl2[s,c]; wave per row i, lanes over s
        const int i = blk * 4 + w;
        const float* wp = Wl1 + (size_t)i * 1280;
        float a0 = 0.f, a1 = 0.f, a2 = 0.f;
        for (int s5 = 0; s5 < 20; ++s5) {
            int s = s5 * 64 + lane;
            float wv = wp[s];
            a0 = fmaf(wv, Wl2[s * 3 + 0], a0);
            a1 = fmaf(wv, Wl2[s * 3 + 1], a1);
            a2 = fmaf(wv, Wl2[s * 3 + 2], a2);
        }
#pragma unroll
        for (int d = 1; d < 64; d <<= 1) {
            a0 += __shfl_xor(a0, d);
            a1 += __shfl_xor(a1, d);
            a2 += __shfl_xor(a2, d);
        }
        if (lane == 0) {
            float* o = ws + OFF_WL12 + i * 4;
            o[0] = a0; o[1] = a1; o[2] = a2; o[3] = 0.f;
        }
    } else if (blk < 160) {
        // root: wave per (b,n), lanes over feature axis, coalesced
        const int wv = (blk - 32) * 4 + w;          // 0..511
        const int b = wv >> 5, n = wv & 31;
        float a0 = 0.f, a1 = 0.f, a2 = 0.f;
#define TREE(T, W, RN, F) { \
        const float* tp = T + (size_t)(b * RN + ((n * RN) >> 5)) * F; \
        for (int k = lane; k < F; k += 64) { \
            float tv = tp[k]; \
            a0 = fmaf(tv, W[k * 3 + 0], a0); \
            a1 = fmaf(tv, W[k * 3 + 1], a1); \
            a2 = fmaf(tv, W[k * 3 + 2], a2); } }
        TREE(t0, Wr0, 1, 96)
        TREE(t1, Wr1, 2, 256)
        TREE(t2, Wr2, 4, 256)
        TREE(t3, Wr3, 8, 256)
        TREE(t4, Wr4, 16, 128)
        TREE(t5, Wr5, 32, 128)
#undef TREE
#pragma unroll
        for (int d = 1; d < 64; d <<= 1) {
            a0 += __shfl_xor(a0, d);
            a1 += __shfl_xor(a1, d);
            a2 += __shfl_xor(a2, d);
        }
        if (lane == 0) {
            float* o = ws + OFF_ROOT + (b * 32 + n) * 4;
            o[0] = a0; o[1] = a1; o[2] = a2;
        }
    } else {
        if (tid < 18) {
            int p = tid / 6, c = tid % 6;
            float a = 0.f;
            for (int o = 0; o < 64; ++o) a = fmaf(c2w[p * 64 + o], c1w[o * 6 + c], a);
            ws[OFF_EFF + tid] = a;
        } else if (tid < 21) {
            int p = tid - 18;
            float a = c2b[p];
            for (int o = 0; o < 64; ++o) a = fmaf(c2w[p * 64 + o], c1b[o], a);
            ws[OFF_EFF + 24 + p] = a;
        }
    }
}

// ---------------- Kernel BX: x = root + leaky(t5@Wb) @ Wl12, pack X ----------------
// grid 512 = 32 n * 16 jt; block 256 = 4 waves; wave w owns d = jt*4+w.
__global__ __launch_bounds__(256) void kBX(const float* __restrict__ t5,
                                           const float* __restrict__ Wb,
                                           float* __restrict__ ws)
{
    const int n = blockIdx.x >> 4, jt = blockIdx.x & 15, tid = threadIdx.x;
    __shared__ float ts[2048];                     // [k][b]
    for (int q = tid; q < 2048; q += 256) {
        int b = q >> 7, k = q & 127;
        ts[k * 16 + b] = t5[b * 4096 + n * 128 + k];
    }
    __syncthreads();
    const int w = tid >> 6, lane = tid & 63;
    const int d = jt * 4 + w;
    const int i0 = lane * 2;
    const float* wp = Wb + (size_t)n * 1048576 + d * 128 + i0;

    float acc[16][2];
#pragma unroll
    for (int b = 0; b < 16; ++b) { acc[b][0] = 0.f; acc[b][1] = 0.f; }

#pragma unroll 4
    for (int k = 0; k < 128; ++k) {
        float2 wv = *(const float2*)(wp + (size_t)k * 8192);
        const float4* tk = (const float4*)(ts + (k << 4));
        float4 t0v = tk[0], t1v = tk[1], t2v = tk[2], t3v = tk[3];
#define FM(BI, TV) acc[BI][0] = fmaf(TV, wv.x, acc[BI][0]); acc[BI][1] = fmaf(TV, wv.y, acc[BI][1]);
        FM(0, t0v.x) FM(1, t0v.y) FM(2, t0v.z) FM(3, t0v.w)
        FM(4, t1v.x) FM(5, t1v.y) FM(6, t1v.z) FM(7, t1v.w)
        FM(8, t2v.x) FM(9, t2v.y) FM(10, t2v.z) FM(11, t2v.w)
        FM(12, t3v.x) FM(13, t3v.y) FM(14, t3v.z) FM(15, t3v.w)
#undef FM
    }

    const float4 wl0 = *(const float4*)(ws + OFF_WL12 + i0 * 4);
    const float4 wl1 = *(const float4*)(ws + OFF_WL12 + (i0 + 1) * 4);
    float P[16][3];
#pragma unroll
    for (int b = 0; b < 16; ++b) {
        float y0 = leaky(acc[b][0]), y1 = leaky(acc[b][1]);
        P[b][0] = fmaf(y1, wl1.x, y0 * wl0.x);
        P[b][1] = fmaf(y1, wl1.y, y0 * wl0.y);
        P[b][2] = fmaf(y1, wl1.z, y0 * wl0.z);
    }
#pragma unroll
    for (int b = 0; b < 16; ++b) {
#pragma unroll
        for (int dd = 1; dd < 64; dd <<= 1) {
            P[b][0] += __shfl_xor(P[b][0], dd);
            P[b][1] += __shfl_xor(P[b][1], dd);
            P[b][2] += __shfl_xor(P[b][2], dd);
        }
    }
    float q0 = P[0][0], q1 = P[0][1], q2 = P[0][2];
#pragma unroll
    for (int b = 1; b < 16; ++b) {
        bool m = (lane == b);
        q0 = m ? P[b][0] : q0;
        q1 = m ? P[b][1] : q1;
        q2 = m ? P[b][2] : q2;
    }
    if (lane < 16) {
        float4 rt = ((const float4*)(ws + OFF_ROOT))[lane * 32 + n];
        float x0 = rt.x + q0, x1 = rt.y + q1, x2 = rt.z + q2;
        float xh = 0.5f * fmaf(x0, x0, fmaf(x1, x1, x2 * x2));   // store xx/2
        ((float4*)(ws + OFF_X))[lane * 2048 + n * 64 + d] = make_float4(x0, x1, x2, xh);
    }
}

// ---------------- Kernel C: exact knn top-8 + fused edge-conv ----------------
// Rank statistic: q = dot(xr,xm) - |xm|^2/2  (order-equivalent to pd for fixed row;
// the per-row constant -|xr|^2/2 cancels). X.w pre-stores |x|^2/2 -> 3-FMA chain.
#define CAP_ 16
#define CSWAPD(a, b) { float _hi = fmaxf(a, b), _lo = fminf(a, b); a = _hi; b = _lo; }
#define INS8(P, s0,s1,s2,s3,s4,s5,s6,s7) \
    s7 = med3f(P, s7, s6); s6 = med3f(P, s6, s5); \
    s5 = med3f(P, s5, s4); s4 = med3f(P, s4, s3); \
    s3 = med3f(P, s3, s2); s2 = med3f(P, s2, s1); \
    s1 = med3f(P, s1, s0); s0 = fmaxf(s0, P);
#define MERGE8(W, s0,s1,s2,s3,s4,s5,s6,s7) { \
    float o0 = __shfl_xor(s0, W), o1 = __shfl_xor(s1, W), o2 = __shfl_xor(s2, W), o3 = __shfl_xor(s3, W); \
    float o4 = __shfl_xor(s4, W), o5 = __shfl_xor(s5, W), o6 = __shfl_xor(s6, W), o7 = __shfl_xor(s7, W); \
    float n0 = fmaxf(s0, o7), n1 = fmaxf(s1, o6), n2 = fmaxf(s2, o5), n3 = fmaxf(s3, o4); \
    float n4 = fmaxf(s4, o3), n5 = fmaxf(s5, o2), n6 = fmaxf(s6, o1), n7 = fmaxf(s7, o0); \
    CSWAPD(n0, n4) CSWAPD(n1, n5) CSWAPD(n2, n6) CSWAPD(n3, n7) \
    CSWAPD(n0, n2) CSWAPD(n1, n3) CSWAPD(n4, n6) CSWAPD(n5, n7) \
    CSWAPD(n0, n1) CSWAPD(n2, n3) CSWAPD(n4, n5) CSWAPD(n6, n7) \
    s0 = n0; s1 = n1; s2 = n2; s3 = n3; s4 = n4; s5 = n5; s6 = n6; s7 = n7; }
#define PDQ(XR, XM) fmaf(XR.x, XM.x, fmaf(XR.y, XM.y, fmaf(XR.z, XM.z, -XM.w)))

__global__ __launch_bounds__(256) void kC(const float* __restrict__ ws,
                                          const float* __restrict__ bias,
                                          float* __restrict__ out)
{
    const int bb = blockIdx.x >> 6, rtile = blockIdx.x & 63, tid = threadIdx.x;
    __shared__ float4 xs[2048];
    __shared__ float eff[32];
    __shared__ int cnt[32];
    __shared__ int lists[32][CAP_];
    __shared__ int sel[32][KNN_];

    const float4* xg = (const float4*)(ws + OFF_X) + bb * 2048;
    for (int q = tid; q < 2048; q += 256) xs[q] = xg[q];
    if (tid < 32) { eff[tid] = ws[OFF_EFF + tid]; cnt[tid] = 0; }
    __syncthreads();

    const int g  = tid >> 5;          // row-group 0..7 (4 rows)
    const int mp = tid & 31;          // m-part (m = mm*32 + mp)
    const int r0 = rtile * 32 + g * 4;
    const float4 xa = xs[r0], xb = xs[r0 + 1], xc = xs[r0 + 2], xd = xs[r0 + 3];

    float A0=-FLT_MAX,A1=-FLT_MAX,A2=-FLT_MAX,A3=-FLT_MAX,A4=-FLT_MAX,A5=-FLT_MAX,A6=-FLT_MAX,A7=-FLT_MAX;
    float B0=-FLT_MAX,B1=-FLT_MAX,B2=-FLT_MAX,B3=-FLT_MAX,B4=-FLT_MAX,B5=-FLT_MAX,B6=-FLT_MAX,B7=-FLT_MAX;
    float C0=-FLT_MAX,C1=-FLT_MAX,C2=-FLT_MAX,C3=-FLT_MAX,C4=-FLT_MAX,C5=-FLT_MAX,C6=-FLT_MAX,C7=-FLT_MAX;
    float D0=-FLT_MAX,D1=-FLT_MAX,D2=-FLT_MAX,D3=-FLT_MAX,D4=-FLT_MAX,D5=-FLT_MAX,D6=-FLT_MAX,D7=-FLT_MAX;

#pragma unroll 4
    for (int mm = 0; mm < 64; ++mm) {
        float4 xm = xs[(mm << 5) | mp];
        float pa = PDQ(xa, xm); INS8(pa, A0,A1,A2,A3,A4,A5,A6,A7)
        float pb = PDQ(xb, xm); INS8(pb, B0,B1,B2,B3,B4,B5,B6,B7)
        float pc = PDQ(xc, xm); INS8(pc, C0,C1,C2,C3,C4,C5,C6,C7)
        float pdv = PDQ(xd, xm); INS8(pdv, D0,D1,D2,D3,D4,D5,D6,D7)
    }
#pragma unroll
    for (int w = 1; w < 32; w <<= 1) {
        MERGE8(w, A0,A1,A2,A3,A4,A5,A6,A7)
        MERGE8(w, B0,B1,B2,B3,B4,B5,B6,B7)
        MERGE8(w, C0,C1,C2,C3,C4,C5,C6,C7)
        MERGE8(w, D0,D1,D2,D3,D4,D5,D6,D7)
    }
    const float Ta = A7, Tb = B7, Tc = C7, Td = D7;   // exact 8th-largest q per row

#pragma unroll 4
    for (int mm = 0; mm < 64; ++mm) {
        int m = (mm << 5) | mp;
        float4 xm = xs[m];
        float pa = PDQ(xa, xm);
        float pb = PDQ(xb, xm);
        float pc = PDQ(xc, xm);
        float pdv = PDQ(xd, xm);
        if (pa >= Ta) { int s = atomicAdd(&cnt[g*4+0], 1); if (s < CAP_) lists[g*4+0][s] = m | ((pa > Ta) ? 0x10000 : 0); }
        if (pb >= Tb) { int s = atomicAdd(&cnt[g*4+1], 1); if (s < CAP_) lists[g*4+1][s] = m | ((pb > Tb) ? 0x10000 : 0); }
        if (pc >= Tc) { int s = atomicAdd(&cnt[g*4+2], 1); if (s < CAP_) lists[g*4+2][s] = m | ((pc > Tc) ? 0x10000 : 0); }
        if (pdv >= Td){ int s = atomicAdd(&cnt[g*4+3], 1); if (s < CAP_) lists[g*4+3][s] = m | ((pdv > Td) ? 0x10000 : 0); }
    }
    __syncthreads();

    const int lr = tid >> 3;
    const int part = tid & 7;
    const int r = rtile * 32 + lr;
    if (part == 0) {
        int c = cnt[lr]; if (c > CAP_) c = CAP_;
        int ng = 0;
        for (int q = 0; q < c; ++q) {
            int v = lists[lr][q];
            if (v & 0x10000) sel[lr][ng++] = v & 0xFFFF;
        }
        int prev = -1;
        while (ng < KNN_) {
            int best = 0x7FFFFFFF;
            for (int q = 0; q < c; ++q) {
                int v = lists[lr][q];
                if (!(v & 0x10000)) {
                    int m = v & 0xFFFF;
                    if (m > prev && m < best) best = m;
                }
            }
            if (best == 0x7FFFFFFF) best = r;
            sel[lr][ng++] = best; prev = best;
        }
    }
    __syncthreads();

    const float4 xr = xs[r];
    const int ms = sel[lr][part];
    const float4 fm = xs[ms];
    const float g0 = fm.x - xr.x, g1 = fm.y - xr.y, g2 = fm.z - xr.z;
    float h0 = eff[24], h1 = eff[25], h2 = eff[26];
    h0 = fmaf(g0, eff[0], h0);  h0 = fmaf(g1, eff[1], h0);  h0 = fmaf(g2, eff[2], h0);
    h0 = fmaf(xr.x, eff[3], h0); h0 = fmaf(xr.y, eff[4], h0); h0 = fmaf(xr.z, eff[5], h0);
    h1 = fmaf(g0, eff[6], h1);  h1 = fmaf(g1, eff[7], h1);  h1 = fmaf(g2, eff[8], h1);
    h1 = fmaf(xr.x, eff[9], h1); h1 = fmaf(xr.y, eff[10], h1); h1 = fmaf(xr.z, eff[11], h1);
    h2 = fmaf(g0, eff[12], h2); h2 = fmaf(g1, eff[13], h2); h2 = fmaf(g2, eff[14], h2);
    h2 = fmaf(xr.x, eff[15], h2); h2 = fmaf(xr.y, eff[16], h2); h2 = fmaf(xr.z, eff[17], h2);
#pragma unroll
    for (int w = 1; w < 8; w <<= 1) {
        h0 = fmaxf(h0, __shfl_xor(h0, w));
        h1 = fmaxf(h1, __shfl_xor(h1, w));
        h2 = fmaxf(h2, __shfl_xor(h2, w));
    }
    if (part == 0) {
        const float* bp = bias + (r & 63) * 3;
        float* op = out + (size_t)(bb * 2048 + r) * 3;
        op[0] = leaky(h0 + bp[0]);
        op[1] = leaky(h1 + bp[1]);
        op[2] = leaky(h2 + bp[2]);
    }
}

extern "C" void kernel_launch(void* const* d_in, const int* in_sizes, int n_in,
                              void* d_out, int out_size, void* d_ws, size_t ws_size,
                              hipStream_t stream)
{
    const float* t0 = (const float*)d_in[0];
    const float* t1 = (const float*)d_in[1];
    const float* t2 = (const float*)d_in[2];
    const float* t3 = (const float*)d_in[3];
    const float* t4 = (const float*)d_in[4];
    const float* t5 = (const float*)d_in[5];
    const float* Wr0 = (const float*)d_in[6];
    const float* Wr1 = (const float*)d_in[7];
    const float* Wr2 = (const float*)d_in[8];
    const float* Wr3 = (const float*)d_in[9];
    const float* Wr4 = (const float*)d_in[10];
    const float* Wr5 = (const float*)d_in[11];
    const float* Wb  = (const float*)d_in[12];
    const float* Wl1 = (const float*)d_in[13];
    const float* Wl2 = (const float*)d_in[14];
    const float* bias = (const float*)d_in[15];
    const float* c1w = (const float*)d_in[16];
    const float* c1b = (const float*)d_in[17];
    const float* c2w = (const float*)d_in[18];
    const float* c2b = (const float*)d_in[19];
    float* ws = (float*)d_ws;
    float* out = (float*)d_out;

    hipLaunchKernelGGL(kA, dim3(161), dim3(256), 0, stream,
                       t0, t1, t2, t3, t4, t5, Wr0, Wr1, Wr2, Wr3, Wr4, Wr5,
                       Wl1, Wl2, c1w, c1b, c2w, c2b, ws);
    hipLaunchKernelGGL(kBX, dim3(512), dim3(256), 0, stream, t5, Wb, ws);
    hipLaunchKernelGGL(kC, dim3(1024), dim3(256), 0, stream, ws, bias, out);
}